// Round 7
// baseline (1013.653 us; speedup 1.0000x reference)
//
#include <hip/hip_runtime.h>

#define DIMC 512
#define HEADS 8
#define HD 64
#define WINS 10
#define SHIFT_SZ 5
#define FRAMES 1000
#define NWIN 100
#define BATCH 64
#define TOKENS 64000
#define HIDDEN 2048

typedef unsigned short u16;
typedef __attribute__((ext_vector_type(8))) short bf16x8;
typedef __attribute__((ext_vector_type(4))) float f32x4;

__device__ __forceinline__ float bf2f(u16 u) { return __uint_as_float(((unsigned)u) << 16); }
__device__ __forceinline__ u16 f2bf(float f) {
    unsigned u = __float_as_uint(f);
    u += 0x7fffu + ((u >> 16) & 1u);
    return (u16)(u >> 16);
}

// ---------------- fp32 -> bf16 weight conversion ----------------
__global__ __launch_bounds__(256) void cvt_kernel(const float* __restrict__ src,
                                                  u16* __restrict__ dst, int n) {
    const int i = (blockIdx.x * 256 + threadIdx.x) * 4;
    if (i < n) {
        const float4 v = *(const float4*)(src + i);
        *(ushort4*)(dst + i) = make_ushort4(f2bf(v.x), f2bf(v.y), f2bf(v.z), f2bf(v.w));
    }
}

// ---------------- LayerNorm: fp32 in -> bf16 out (rolled by -SH) ----------------
template <int SH>
__global__ __launch_bounds__(256) void ln_kernel(const float* __restrict__ x,
                                                 const float* __restrict__ w,
                                                 const float* __restrict__ b,
                                                 u16* __restrict__ out) {
    const int wave = threadIdx.x >> 6, lane = threadIdx.x & 63;
    const int row = blockIdx.x * 4 + wave;
    const float4* rp = (const float4*)(x + (size_t)row * DIMC);
    const float4 v0 = rp[lane];
    const float4 v1 = rp[64 + lane];
    float f[8] = {v0.x, v0.y, v0.z, v0.w, v1.x, v1.y, v1.z, v1.w};
    float sum = 0.f, sq = 0.f;
#pragma unroll
    for (int i = 0; i < 8; i++) { sum += f[i]; sq += f[i] * f[i]; }
#pragma unroll
    for (int off = 32; off >= 1; off >>= 1) {
        sum += __shfl_xor(sum, off);
        sq += __shfl_xor(sq, off);
    }
    const float mean = sum * (1.f / DIMC);
    const float var = sq * (1.f / DIMC) - mean * mean;
    const float rstd = rsqrtf(var + 1e-5f);

    const float4 w0 = ((const float4*)w)[lane], w1 = ((const float4*)w)[64 + lane];
    const float4 b0 = ((const float4*)b)[lane], b1 = ((const float4*)b)[64 + lane];
    const float wf[8] = {w0.x, w0.y, w0.z, w0.w, w1.x, w1.y, w1.z, w1.w};
    const float bf[8] = {b0.x, b0.y, b0.z, b0.w, b1.x, b1.y, b1.z, b1.w};
    u16 o[8];
#pragma unroll
    for (int i = 0; i < 8; i++) o[i] = f2bf((f[i] - mean) * rstd * wf[i] + bf[i]);

    int dst = row;
    if (SH) {
        int bb = row / FRAMES;
        int t = row - bb * FRAMES;
        int td = t - SH; if (td < 0) td += FRAMES;
        dst = bb * FRAMES + td;
    }
    u16* op = out + (size_t)dst * DIMC;
    *(ushort4*)(op + 4 * lane) = make_ushort4(o[0], o[1], o[2], o[3]);
    *(ushort4*)(op + 256 + 4 * lane) = make_ushort4(o[4], o[5], o[6], o[7]);
}

// ---------------- 256x256 GEMM, BK=32, 2-phase prefetch, granule-XOR LDS ----------------
// C = A[M,K](bf16) * W[Nn,K](bf16)^T + bias.
// 512 threads = 8 waves (2M x 4N); per-wave output 128x64; acc[8][4] f32x4.
// LDS 64 KiB: 2 buffers x (A 256x32 | B 256x32) bf16, linear rows, granule-XOR'd content.
// MODE 0: bf16 out (qkv). MODE 1: proj fp32 roll(+SHIFT)+residual. MODE 2: fc1+GELU bf16.
// MODE 3: fc2 fp32 +residual (in-place ok).
#define GLD16(gp, lp)                                                                     \
    __builtin_amdgcn_global_load_lds((const __attribute__((address_space(1))) void*)(gp), \
                                     (__attribute__((address_space(3))) void*)(lp), 16, 0, 0)

template <int MODE>
__global__ __launch_bounds__(512, 2) void gemm256(const u16* __restrict__ A,
                                                  const u16* __restrict__ W,
                                                  const float* __restrict__ bias,
                                                  u16* __restrict__ Cb,
                                                  float* __restrict__ Cf,
                                                  const float* __restrict__ Rf,
                                                  int Nn, int K, int nbn) {
    __shared__ __align__(16) u16 smem[32768];  // 64 KiB
    const int tid = threadIdx.x;
    const int w = tid >> 6, l = tid & 63;
    const int wr = w >> 2, wc = w & 3;
    const int lrow = l & 15, lq = l >> 4;

    // T1: bijective XCD remap; consecutive swz share bm (A panel)
    const int nwg = gridDim.x;
    const int q8 = nwg >> 3, r8 = nwg & 7;
    const int xcd = blockIdx.x & 7, bidx = blockIdx.x >> 3;
    const int swz = (xcd < r8 ? xcd * (q8 + 1) : r8 * (q8 + 1) + (xcd - r8) * q8) + bidx;
    const int bm = swz / nbn, bn = swz - bm * nbn;

    f32x4 acc[8][4];
#pragma unroll
    for (int m = 0; m < 8; m++)
#pragma unroll
        for (int n = 0; n < 4; n++) acc[m][n] = (f32x4)0.0f;

    // staging: lane covers row = i*128 + w*16 + (l>>2), phys granule l&3,
    // logical granule = (l&3) ^ ((l>>3)&3)  (== phys ^ ((row>>1)&3))
    const int srow = w * 16 + (l >> 2);
    const int gsrc8 = (((l & 3) ^ ((l >> 3) & 3)) << 3);
    const u16* Ag = A + (size_t)(bm * 256 + srow) * K + gsrc8;
    const u16* Bg = W + (size_t)(bn * 256 + srow) * K + gsrc8;
    const size_t aoff = (size_t)128 * K;

#define STAGE256(buf, kt) do {                                          \
        GLD16(Ag + (kt), smem + (buf) * 16384 + w * 512);               \
        GLD16(Ag + aoff + (kt), smem + (buf) * 16384 + 4096 + w * 512); \
        GLD16(Bg + (kt), smem + (buf) * 16384 + 8192 + w * 512);        \
        GLD16(Bg + aoff + (kt), smem + (buf) * 16384 + 12288 + w * 512);\
    } while (0)

    // read: phys granule = logical(lq) ^ ((row>>1)&3) = lq ^ ((lrow>>1)&3)
    const int agp8 = ((lq ^ ((lrow >> 1) & 3)) << 3);
    const int abase = (wr * 128 + lrow) * 32 + agp8;          // + m*512
    const int bbase = 8192 + (wc * 64 + lrow) * 32 + agp8;    // + n*512

    auto compute = [&](int buf) {
        const u16* sb = smem + buf * 16384;
        bf16x8 af[8], bv[4];
#pragma unroll
        for (int m = 0; m < 8; m++) af[m] = *(const bf16x8*)(sb + abase + m * 512);
#pragma unroll
        for (int n = 0; n < 4; n++) bv[n] = *(const bf16x8*)(sb + bbase + n * 512);
#pragma unroll
        for (int m = 0; m < 8; m++)
#pragma unroll
            for (int n = 0; n < 4; n++)
                acc[m][n] = __builtin_amdgcn_mfma_f32_16x16x32_bf16(af[m], bv[n], acc[m][n], 0, 0, 0);
    };

    STAGE256(0, 0);
    __syncthreads();
    int cur = 0;
    for (int kt = 32; kt < K; kt += 32) {
        STAGE256(cur ^ 1, kt);   // prefetch next tile
        compute(cur);            // MFMA on current tile hides load latency
        __syncthreads();         // vmcnt(0)+lgkmcnt(0)+barrier: staged data visible
        cur ^= 1;
    }
    compute(cur);

    if (MODE == 0 || MODE == 2) {
        // ---- bf16 epilogue: two 128-row swizzled LDS bounce passes ----
#pragma unroll
        for (int half = 0; half < 2; half++) {
            __syncthreads();
            if (wr == half) {
#pragma unroll
                for (int n = 0; n < 4; n++) {
                    const int col = wc * 64 + n * 16 + lrow;
                    const float bcol = bias[bn * 256 + col];
#pragma unroll
                    for (int m = 0; m < 8; m++) {
                        const int rb = m * 16 + lq * 4;
#pragma unroll
                        for (int r = 0; r < 4; r++) {
                            float v = acc[m][n][r] + bcol;
                            if (MODE == 2) {
                                const float u2 = v * (0.7978845608f + 0.0356774081f * v * v);
                                v = v / (1.f + __expf(-2.f * u2));
                            }
                            const int rl = rb + r;
                            smem[rl * 256 + (((col >> 3) ^ (rl & 7)) << 3) + (col & 7)] = f2bf(v);
                        }
                    }
                }
            }
            __syncthreads();
            const int c8 = tid & 31;
#pragma unroll
            for (int it = 0; it < 8; it++) {
                const int rl = it * 16 + (tid >> 5);
                const uint4 val = *(const uint4*)(smem + rl * 256 + ((c8 ^ (rl & 7)) << 3));
                *(uint4*)(Cb + (size_t)(bm * 256 + half * 128 + rl) * Nn + bn * 256 + c8 * 8) = val;
            }
        }
    } else {
        // ---- fp32 epilogue with residual (proj / fc2) ----
#pragma unroll
        for (int n = 0; n < 4; n++) {
            const int col = bn * 256 + wc * 64 + n * 16 + lrow;
            const float bcol = bias[col];
#pragma unroll
            for (int m = 0; m < 8; m++) {
                const int row0 = bm * 256 + wr * 128 + m * 16 + lq * 4;
#pragma unroll
                for (int r = 0; r < 4; r++) {
                    const int row = row0 + r;
                    float v = acc[m][n][r] + bcol;
                    if (MODE == 1) {
                        int bb = row / FRAMES;
                        int tr = row - bb * FRAMES;
                        int td = tr + SHIFT_SZ; if (td >= FRAMES) td -= FRAMES;
                        size_t dr = (size_t)(bb * FRAMES + td) * DIMC + col;
                        Cf[dr] = v + Rf[dr];
                    } else {
                        size_t dr = (size_t)row * Nn + col;
                        Cf[dr] = v + Rf[dr];
                    }
                }
            }
        }
    }
#undef STAGE256
}

// ---------------- Windowed attention: one block per window (chunked) ----------------
__global__ __launch_bounds__(256) void attn_kernel(const u16* __restrict__ qkv_c,
                                                   const float* __restrict__ relb,
                                                   u16* __restrict__ out,
                                                   int win0) {
    __shared__ __align__(16) u16 kv[WINS * 3 * DIMC];  // 30720 B
    __shared__ float S[HEADS][WINS][WINS];
    const int tid = threadIdx.x;
    const int win = win0 + blockIdx.x;
    const u16* src = qkv_c + (size_t)blockIdx.x * (WINS * 3 * DIMC);
    for (int idx = tid * 8; idx < WINS * 3 * DIMC; idx += 2048)
        *(uint4*)(kv + idx) = *(const uint4*)(src + idx);
    __syncthreads();

    const bool lastw = (win % NWIN) == (NWIN - 1);
    for (int e = tid; e < HEADS * WINS * WINS; e += 256) {
        const int hh = e / (WINS * WINS);
        const int rem = e - hh * WINS * WINS;
        const int i = rem / WINS, j = rem - (rem / WINS) * WINS;
        const u16* qp = kv + i * (3 * DIMC) + hh * HD;
        const u16* kp = kv + j * (3 * DIMC) + DIMC + hh * HD;
        float s = 0.f;
#pragma unroll
        for (int c = 0; c < 64; c++) s += bf2f(qp[c]) * bf2f(kp[c]);
        s *= 0.125f;
        s += relb[(i - j + WINS - 1) * HEADS + hh];
        if (lastw && ((i < SHIFT_SZ) != (j < SHIFT_SZ))) s -= 100.f;
        S[hh][i][j] = s;
    }
    __syncthreads();

    if (tid < HEADS * WINS) {
        const int hh = tid / WINS, i = tid - (tid / WINS) * WINS;
        float m = -1e30f;
#pragma unroll
        for (int j = 0; j < WINS; j++) m = fmaxf(m, S[hh][i][j]);
        float e[WINS], sum = 0.f;
#pragma unroll
        for (int j = 0; j < WINS; j++) { e[j] = __expf(S[hh][i][j] - m); sum += e[j]; }
        const float inv = 1.f / sum;
#pragma unroll
        for (int j = 0; j < WINS; j++) S[hh][i][j] = e[j] * inv;
    }
    __syncthreads();

    {
        const int hh = tid >> 5, dl = tid & 31;
#pragma unroll
        for (int half = 0; half < 2; half++) {
            const int d = dl + half * 32;
            float vv[WINS];
#pragma unroll
            for (int j = 0; j < WINS; j++) vv[j] = bf2f(kv[j * (3 * DIMC) + 2 * DIMC + hh * HD + d]);
#pragma unroll
            for (int i = 0; i < WINS; i++) {
                float o = 0.f;
#pragma unroll
                for (int j = 0; j < WINS; j++) o += S[hh][i][j] * vv[j];
                out[(size_t)(win * WINS + i) * DIMC + hh * HD + d] = f2bf(o);
            }
        }
    }
}

extern "C" void kernel_launch(void* const* d_in, const int* in_sizes, int n_in,
                              void* d_out, int out_size, void* d_ws, size_t ws_size,
                              hipStream_t stream) {
    const float* x     = (const float*)d_in[0];
    const float* n1w   = (const float*)d_in[1];
    const float* n1b   = (const float*)d_in[2];
    const float* qkvw  = (const float*)d_in[3];
    const float* qkvb  = (const float*)d_in[4];
    const float* relb  = (const float*)d_in[5];
    const float* projw = (const float*)d_in[6];
    const float* projb = (const float*)d_in[7];
    const float* n2w   = (const float*)d_in[8];
    const float* n2b   = (const float*)d_in[9];
    const float* fc1w  = (const float*)d_in[10];
    const float* fc1b  = (const float*)d_in[11];
    const float* fc2w  = (const float*)d_in[12];
    const float* fc2b  = (const float*)d_in[13];

    float* outp = (float*)d_out;      // also serves as x2 (proj writes, fc2 RMWs)
    char* ws = (char*)d_ws;
    u16* wb_qkv  = (u16*)(ws);
    u16* wb_proj = (u16*)(ws + 1572864);
    u16* wb_fc1  = (u16*)(ws + 2097152);
    u16* wb_fc2  = (u16*)(ws + 4194304);
    u16* r0  = (u16*)(ws + 6291456);   // 65.536 MB: h -> attn_out -> h2 (bf16)
    u16* big = (u16*)(ws + 71827456);  // chunked qkv / chunked fc1-activation (bf16)

    // 0) weights fp32 -> bf16
    cvt_kernel<<<768, 256, 0, stream>>>(qkvw, wb_qkv, 786432);
    cvt_kernel<<<256, 256, 0, stream>>>(projw, wb_proj, 262144);
    cvt_kernel<<<1024, 256, 0, stream>>>(fc1w, wb_fc1, 1048576);
    cvt_kernel<<<1024, 256, 0, stream>>>(fc2w, wb_fc2, 1048576);

    const size_t avail = ws_size > (size_t)71827456 ? ws_size - (size_t)71827456 : 0;
    // chunk rows must be multiples of 256 (tile) and 640 (windows, qkv only)
    // qkv: nc1=2 -> 32000 rows (98.3 MB). mlp: nc2=2 -> 32000 rows (g=131 MB) else 5 (52.4 MB)
    const int nc1 = (avail >= (size_t)98304000) ? 2 : (avail >= (size_t)19660800) ? 10 : 50;
    const int nc2 = (avail >= (size_t)131072000) ? 2 : (avail >= (size_t)52428800) ? 5 : 25;

    // 1) h = LN1(x), rolled by -SHIFT  (fp32 -> bf16)
    ln_kernel<SHIFT_SZ><<<TOKENS / 4, 256, 0, stream>>>(x, n1w, n1b, r0);

    // 2+3) qkv GEMM + windowed attention, chunked over token rows
    const int rows1 = TOKENS / nc1;
    for (int c = 0; c < nc1; ++c) {
        const int row0 = c * rows1;
        gemm256<0><<<(rows1 / 256) * 6, 512, 0, stream>>>(
            r0 + (size_t)row0 * DIMC, wb_qkv, qkvb, big, nullptr, nullptr, 1536, DIMC, 6);
        attn_kernel<<<rows1 / WINS, 256, 0, stream>>>(big, relb, r0, row0 / WINS);
    }

    // 4) x2 = x + roll(attn_out @ proj_w^T + proj_b, +SHIFT)  -> d_out (fp32)
    gemm256<1><<<(TOKENS / 256) * 2, 512, 0, stream>>>(
        r0, wb_proj, projb, nullptr, outp, x, DIMC, DIMC, 2);

    // 5) h2 = LN2(x2) -> r0 (bf16)
    ln_kernel<0><<<TOKENS / 4, 256, 0, stream>>>(outp, n2w, n2b, r0);

    // 6+7) MLP chunked: g = gelu(h2 @ fc1^T) (bf16); out = x2 + g @ fc2^T (fp32 RMW)
    const int rows2 = TOKENS / nc2;
    for (int c = 0; c < nc2; ++c) {
        const int row0 = c * rows2;
        gemm256<2><<<(rows2 / 256) * 8, 512, 0, stream>>>(
            r0 + (size_t)row0 * DIMC, wb_fc1, fc1b, big, nullptr, nullptr, HIDDEN, DIMC, 8);
        gemm256<3><<<(rows2 / 256) * 2, 512, 0, stream>>>(
            big, wb_fc2, fc2b, nullptr, outp + (size_t)row0 * DIMC, outp + (size_t)row0 * DIMC, DIMC, HIDDEN, 2);
    }
}

// Round 8
// 902.850 us; speedup vs baseline: 1.1227x; 1.1227x over previous
//
#include <hip/hip_runtime.h>

#define DIMC 512
#define HEADS 8
#define HD 64
#define WINS 10
#define SHIFT_SZ 5
#define FRAMES 1000
#define NWIN 100
#define BATCH 64
#define TOKENS 64000
#define HIDDEN 2048

typedef unsigned short u16;
typedef __attribute__((ext_vector_type(8))) short bf16x8;
typedef __attribute__((ext_vector_type(4))) float f32x4;

__device__ __forceinline__ float bf2f(u16 u) { return __uint_as_float(((unsigned)u) << 16); }
__device__ __forceinline__ u16 f2bf(float f) {
    unsigned u = __float_as_uint(f);
    u += 0x7fffu + ((u >> 16) & 1u);
    return (u16)(u >> 16);
}

// ---------------- fp32 -> bf16 weight conversion ----------------
__global__ __launch_bounds__(256) void cvt_kernel(const float* __restrict__ src,
                                                  u16* __restrict__ dst, int n) {
    const int i = (blockIdx.x * 256 + threadIdx.x) * 4;
    if (i < n) {
        const float4 v = *(const float4*)(src + i);
        *(ushort4*)(dst + i) = make_ushort4(f2bf(v.x), f2bf(v.y), f2bf(v.z), f2bf(v.w));
    }
}

// ---------------- LayerNorm fp32-in: bf16 out rolled by -SH ----------------
template <int SH>
__global__ __launch_bounds__(256) void ln_kernel(const float* __restrict__ x,
                                                 const float* __restrict__ w,
                                                 const float* __restrict__ b,
                                                 u16* __restrict__ out) {
    const int wave = threadIdx.x >> 6, lane = threadIdx.x & 63;
    const int row = blockIdx.x * 4 + wave;
    const float4* rp = (const float4*)(x + (size_t)row * DIMC);
    const float4 v0 = rp[lane];
    const float4 v1 = rp[64 + lane];
    float f[8] = {v0.x, v0.y, v0.z, v0.w, v1.x, v1.y, v1.z, v1.w};
    float sum = 0.f, sq = 0.f;
#pragma unroll
    for (int i = 0; i < 8; i++) { sum += f[i]; sq += f[i] * f[i]; }
#pragma unroll
    for (int off = 32; off >= 1; off >>= 1) {
        sum += __shfl_xor(sum, off);
        sq += __shfl_xor(sq, off);
    }
    const float mean = sum * (1.f / DIMC);
    const float var = sq * (1.f / DIMC) - mean * mean;
    const float rstd = rsqrtf(var + 1e-5f);

    const float4 w0 = ((const float4*)w)[lane], w1 = ((const float4*)w)[64 + lane];
    const float4 b0 = ((const float4*)b)[lane], b1 = ((const float4*)b)[64 + lane];
    const float wf[8] = {w0.x, w0.y, w0.z, w0.w, w1.x, w1.y, w1.z, w1.w};
    const float bf[8] = {b0.x, b0.y, b0.z, b0.w, b1.x, b1.y, b1.z, b1.w};
    u16 o[8];
#pragma unroll
    for (int i = 0; i < 8; i++) o[i] = f2bf((f[i] - mean) * rstd * wf[i] + bf[i]);

    int dst = row;
    if (SH) {
        int bb = row / FRAMES;
        int t = row - bb * FRAMES;
        int td = t - SH; if (td < 0) td += FRAMES;
        dst = bb * FRAMES + td;
    }
    u16* op = out + (size_t)dst * DIMC;
    *(ushort4*)(op + 4 * lane) = make_ushort4(o[0], o[1], o[2], o[3]);
    *(ushort4*)(op + 256 + 4 * lane) = make_ushort4(o[4], o[5], o[6], o[7]);
}

// ---------------- LayerNorm bf16-in (for LN2 over x2b) ----------------
__global__ __launch_bounds__(256) void ln_kernel_bf(const u16* __restrict__ x,
                                                    const float* __restrict__ w,
                                                    const float* __restrict__ b,
                                                    u16* __restrict__ out) {
    const int wave = threadIdx.x >> 6, lane = threadIdx.x & 63;
    const int row = blockIdx.x * 4 + wave;
    const uint4 v = ((const uint4*)(x + (size_t)row * DIMC))[lane];
    const unsigned uv[4] = {v.x, v.y, v.z, v.w};
    float f[8];
    float sum = 0.f, sq = 0.f;
#pragma unroll
    for (int i = 0; i < 4; i++) {
        float a = __uint_as_float(uv[i] << 16);
        float c = __uint_as_float(uv[i] & 0xffff0000u);
        f[2 * i] = a; f[2 * i + 1] = c;
        sum += a + c; sq += a * a + c * c;
    }
#pragma unroll
    for (int off = 32; off >= 1; off >>= 1) {
        sum += __shfl_xor(sum, off);
        sq += __shfl_xor(sq, off);
    }
    const float mean = sum * (1.f / DIMC);
    const float var = sq * (1.f / DIMC) - mean * mean;
    const float rstd = rsqrtf(var + 1e-5f);

    const float4 w0 = ((const float4*)w)[2 * lane], w1 = ((const float4*)w)[2 * lane + 1];
    const float4 b0 = ((const float4*)b)[2 * lane], b1 = ((const float4*)b)[2 * lane + 1];
    const float wf[8] = {w0.x, w0.y, w0.z, w0.w, w1.x, w1.y, w1.z, w1.w};
    const float bf[8] = {b0.x, b0.y, b0.z, b0.w, b1.x, b1.y, b1.z, b1.w};
    u16 o[8];
#pragma unroll
    for (int i = 0; i < 8; i++) o[i] = f2bf((f[i] - mean) * rstd * wf[i] + bf[i]);
    uint4 ov;
    ov.x = (unsigned)o[0] | ((unsigned)o[1] << 16);
    ov.y = (unsigned)o[2] | ((unsigned)o[3] << 16);
    ov.z = (unsigned)o[4] | ((unsigned)o[5] << 16);
    ov.w = (unsigned)o[6] | ((unsigned)o[7] << 16);
    ((uint4*)(out + (size_t)row * DIMC))[lane] = ov;
}

// ---------------- GEMM: C = A[M,K](bf16) * W[Nn,K](bf16)^T + bias ----------------
// 128x128 tile, BK=64 (two 32-col planes), 2-barrier loop, T1 XCD-bijective remap.
// MODE 0: bf16 out (qkv).          MODE 2: fc1 + fast GELU, bf16 out.
// MODE 1: proj -> x2b bf16 at rolled rows, += fp32 x residual (read rolled).
// MODE 3: fc2 -> fp32 out, += bf16 x2b residual.
#define GLD16(gp, lp)                                                                     \
    __builtin_amdgcn_global_load_lds((const __attribute__((address_space(1))) void*)(gp), \
                                     (__attribute__((address_space(3))) void*)(lp), 16, 0, 0)

template <int MODE>
__global__ __launch_bounds__(256) void gemm_bt(const u16* __restrict__ A,
                                               const u16* __restrict__ W,
                                               const float* __restrict__ bias,
                                               u16* __restrict__ Cb,
                                               float* __restrict__ Cf,
                                               const float* __restrict__ Rf,
                                               const u16* __restrict__ Rb,
                                               int Nn, int K, int nbn) {
    __shared__ __align__(16) u16 smem[128 * 128];  // 32 KiB: staging, then C-bounce
    u16* As = smem;
    u16* Bs = smem + 128 * 64;
    const int tid = threadIdx.x;
    const int w = tid >> 6, l = tid & 63;

    const int nwg = gridDim.x;
    const int q8 = nwg >> 3, r8 = nwg & 7;
    const int xcd = blockIdx.x & 7, bidx = blockIdx.x >> 3;
    const int swz = (xcd < r8 ? xcd * (q8 + 1) : r8 * (q8 + 1) + (xcd - r8) * q8) + bidx;
    const int bm = swz / nbn, bn = swz - bm * nbn;

    const int wr = w >> 1, wc = w & 1;

    f32x4 acc[4][4];
#pragma unroll
    for (int m = 0; m < 4; m++)
#pragma unroll
        for (int n = 0; n < 4; n++) acc[m][n] = (f32x4)0.0f;

    const u16* Ag = A + (size_t)(bm * 128 + (tid >> 2)) * K + (tid & 3) * 8;
    const u16* Bg = W + (size_t)(bn * 128 + (tid >> 2)) * K + (tid & 3) * 8;
    const size_t rowoff = (size_t)64 * K;
    const int lb = w * 512;

    const int lrow = l & 15, lk = (l >> 4) * 8;
    const int arow = (wr * 64 + lrow) * 32 + lk;
    const int brow = (wc * 64 + lrow) * 32 + lk;

    for (int kt = 0; kt < K; kt += 64) {
        GLD16(Ag + kt, As + lb);
        GLD16(Ag + rowoff + kt, As + 2048 + lb);
        GLD16(Ag + kt + 32, As + 4096 + lb);
        GLD16(Ag + rowoff + kt + 32, As + 6144 + lb);
        GLD16(Bg + kt, Bs + lb);
        GLD16(Bg + rowoff + kt, Bs + 2048 + lb);
        GLD16(Bg + kt + 32, Bs + 4096 + lb);
        GLD16(Bg + rowoff + kt + 32, Bs + 6144 + lb);
        __syncthreads();
#pragma unroll
        for (int p = 0; p < 2; p++) {
            bf16x8 af[4], bv[4];
#pragma unroll
            for (int m = 0; m < 4; m++)
                af[m] = *(const bf16x8*)(As + p * 4096 + arow + m * 512);
#pragma unroll
            for (int n = 0; n < 4; n++)
                bv[n] = *(const bf16x8*)(Bs + p * 4096 + brow + n * 512);
#pragma unroll
            for (int m = 0; m < 4; m++)
#pragma unroll
                for (int n = 0; n < 4; n++)
                    acc[m][n] = __builtin_amdgcn_mfma_f32_16x16x32_bf16(af[m], bv[n], acc[m][n], 0, 0, 0);
        }
        __syncthreads();
    }

    if (MODE == 0 || MODE == 1 || MODE == 2) {
        // ---- bf16 epilogue: swizzled LDS bounce -> coalesced 16B stores ----
#pragma unroll
        for (int n = 0; n < 4; n++) {
            const int col = wc * 64 + n * 16 + lrow;
            const float bcol = bias[bn * 128 + col];
#pragma unroll
            for (int m = 0; m < 4; m++) {
                const int rb2 = wr * 64 + m * 16 + (l >> 4) * 4;
#pragma unroll
                for (int r = 0; r < 4; r++) {
                    float v = acc[m][n][r] + bcol;
                    if (MODE == 2) {
                        const float u2 = v * (0.7978845608f + 0.0356774081f * v * v);
                        v = v / (1.f + __expf(-2.f * u2));
                    }
                    const int row = rb2 + r;
                    smem[row * 128 + (col ^ ((row & 7) << 3))] = f2bf(v);
                }
            }
        }
        __syncthreads();
        const int cl = lrow * 8;
#pragma unroll
        for (int i = 0; i < 8; i++) {
            const int rl = i * 16 + w * 4 + (l >> 4);
            uint4 val = *(const uint4*)(smem + rl * 128 + (cl ^ ((rl & 7) << 3)));
            if (MODE == 1) {
                // rolled destination row + fp32 residual read at same dst
                const int grow = bm * 128 + rl;
                int bb = grow / FRAMES;
                int tr = grow - bb * FRAMES;
                int td = tr + SHIFT_SZ; if (td >= FRAMES) td -= FRAMES;
                const size_t drow = (size_t)(bb * FRAMES + td) * DIMC + bn * 128 + cl;
                const float4 rA = *(const float4*)(Rf + drow);
                const float4 rB = *(const float4*)(Rf + drow + 4);
                const u16* vp = (const u16*)&val;
                u16 o[8];
                o[0] = f2bf(bf2f(vp[0]) + rA.x); o[1] = f2bf(bf2f(vp[1]) + rA.y);
                o[2] = f2bf(bf2f(vp[2]) + rA.z); o[3] = f2bf(bf2f(vp[3]) + rA.w);
                o[4] = f2bf(bf2f(vp[4]) + rB.x); o[5] = f2bf(bf2f(vp[5]) + rB.y);
                o[6] = f2bf(bf2f(vp[6]) + rB.z); o[7] = f2bf(bf2f(vp[7]) + rB.w);
                uint4 ov;
                ov.x = (unsigned)o[0] | ((unsigned)o[1] << 16);
                ov.y = (unsigned)o[2] | ((unsigned)o[3] << 16);
                ov.z = (unsigned)o[4] | ((unsigned)o[5] << 16);
                ov.w = (unsigned)o[6] | ((unsigned)o[7] << 16);
                *(uint4*)(Cb + drow) = ov;
            } else {
                *(uint4*)(Cb + (size_t)(bm * 128 + rl) * Nn + bn * 128 + cl) = val;
            }
        }
    } else {
        // ---- MODE 3: fp32 out with bf16 residual ----
#pragma unroll
        for (int n = 0; n < 4; n++) {
            const int col = bn * 128 + wc * 64 + n * 16 + lrow;
            const float bcol = bias[col];
#pragma unroll
            for (int m = 0; m < 4; m++) {
                const int row0 = bm * 128 + wr * 64 + m * 16 + (l >> 4) * 4;
#pragma unroll
                for (int r = 0; r < 4; r++) {
                    const size_t dr = (size_t)(row0 + r) * Nn + col;
                    Cf[dr] = acc[m][n][r] + bcol + bf2f(Rb[dr]);
                }
            }
        }
    }
}

// ---------------- Windowed attention: one block per window (chunked) ----------------
__global__ __launch_bounds__(256) void attn_kernel(const u16* __restrict__ qkv_c,
                                                   const float* __restrict__ relb,
                                                   u16* __restrict__ out,
                                                   int win0) {
    __shared__ __align__(16) u16 kv[WINS * 3 * DIMC];  // 30720 B
    __shared__ float S[HEADS][WINS][WINS];
    const int tid = threadIdx.x;
    const int win = win0 + blockIdx.x;
    const u16* src = qkv_c + (size_t)blockIdx.x * (WINS * 3 * DIMC);
    for (int idx = tid * 8; idx < WINS * 3 * DIMC; idx += 2048)
        *(uint4*)(kv + idx) = *(const uint4*)(src + idx);
    __syncthreads();

    const bool lastw = (win % NWIN) == (NWIN - 1);
    for (int e = tid; e < HEADS * WINS * WINS; e += 256) {
        const int hh = e / (WINS * WINS);
        const int rem = e - hh * WINS * WINS;
        const int i = rem / WINS, j = rem - (rem / WINS) * WINS;
        const u16* qp = kv + i * (3 * DIMC) + hh * HD;
        const u16* kp = kv + j * (3 * DIMC) + DIMC + hh * HD;
        float s = 0.f;
#pragma unroll
        for (int c = 0; c < 64; c++) s += bf2f(qp[c]) * bf2f(kp[c]);
        s *= 0.125f;
        s += relb[(i - j + WINS - 1) * HEADS + hh];
        if (lastw && ((i < SHIFT_SZ) != (j < SHIFT_SZ))) s -= 100.f;
        S[hh][i][j] = s;
    }
    __syncthreads();

    if (tid < HEADS * WINS) {
        const int hh = tid / WINS, i = tid - (tid / WINS) * WINS;
        float m = -1e30f;
#pragma unroll
        for (int j = 0; j < WINS; j++) m = fmaxf(m, S[hh][i][j]);
        float e[WINS], sum = 0.f;
#pragma unroll
        for (int j = 0; j < WINS; j++) { e[j] = __expf(S[hh][i][j] - m); sum += e[j]; }
        const float inv = 1.f / sum;
#pragma unroll
        for (int j = 0; j < WINS; j++) S[hh][i][j] = e[j] * inv;
    }
    __syncthreads();

    {
        const int hh = tid >> 5, dl = tid & 31;
#pragma unroll
        for (int half = 0; half < 2; half++) {
            const int d = dl + half * 32;
            float vv[WINS];
#pragma unroll
            for (int j = 0; j < WINS; j++) vv[j] = bf2f(kv[j * (3 * DIMC) + 2 * DIMC + hh * HD + d]);
#pragma unroll
            for (int i = 0; i < WINS; i++) {
                float o = 0.f;
#pragma unroll
                for (int j = 0; j < WINS; j++) o += S[hh][i][j] * vv[j];
                out[(size_t)(win * WINS + i) * DIMC + hh * HD + d] = f2bf(o);
            }
        }
    }
}

extern "C" void kernel_launch(void* const* d_in, const int* in_sizes, int n_in,
                              void* d_out, int out_size, void* d_ws, size_t ws_size,
                              hipStream_t stream) {
    const float* x     = (const float*)d_in[0];
    const float* n1w   = (const float*)d_in[1];
    const float* n1b   = (const float*)d_in[2];
    const float* qkvw  = (const float*)d_in[3];
    const float* qkvb  = (const float*)d_in[4];
    const float* relb  = (const float*)d_in[5];
    const float* projw = (const float*)d_in[6];
    const float* projb = (const float*)d_in[7];
    const float* n2w   = (const float*)d_in[8];
    const float* n2b   = (const float*)d_in[9];
    const float* fc1w  = (const float*)d_in[10];
    const float* fc1b  = (const float*)d_in[11];
    const float* fc2w  = (const float*)d_in[12];
    const float* fc2b  = (const float*)d_in[13];

    float* outp = (float*)d_out;       // final fp32 output (written once, by fc2)
    char* ws = (char*)d_ws;
    u16* wb_qkv  = (u16*)(ws);
    u16* wb_proj = (u16*)(ws + 1572864);
    u16* wb_fc1  = (u16*)(ws + 2097152);
    u16* wb_fc2  = (u16*)(ws + 4194304);
    u16* r0  = (u16*)(ws + 6291456);    // 65.536 MB: h -> attn_out -> h2 (bf16)
    u16* x2b = (u16*)(ws + 71827456);   // 65.536 MB: x2 in bf16
    u16* big = (u16*)(ws + 137363456);  // chunked qkv / fc1-activation (bf16)

    // 0) weights fp32 -> bf16
    cvt_kernel<<<768, 256, 0, stream>>>(qkvw, wb_qkv, 786432);
    cvt_kernel<<<256, 256, 0, stream>>>(projw, wb_proj, 262144);
    cvt_kernel<<<1024, 256, 0, stream>>>(fc1w, wb_fc1, 1048576);
    cvt_kernel<<<1024, 256, 0, stream>>>(fc2w, wb_fc2, 1048576);

    const size_t avail = ws_size > (size_t)137363456 ? ws_size - (size_t)137363456 : 0;
    const int nc1 = (avail >= (size_t)98304000) ? 2
                  : (avail >= (size_t)49152000) ? 4 : (avail >= (size_t)19660800) ? 10 : 50;
    const int nc2 = (avail >= (size_t)65536000) ? 4 : (avail >= (size_t)26214400) ? 10 : 50;

    // 1) h = LN1(x), rolled by -SHIFT
    ln_kernel<SHIFT_SZ><<<TOKENS / 4, 256, 0, stream>>>(x, n1w, n1b, r0);

    // 2+3) qkv GEMM + windowed attention, chunked
    const int rows1 = TOKENS / nc1;
    for (int c = 0; c < nc1; ++c) {
        const int row0 = c * rows1;
        gemm_bt<0><<<(rows1 / 128) * 12, 256, 0, stream>>>(
            r0 + (size_t)row0 * DIMC, wb_qkv, qkvb, big, nullptr, nullptr, nullptr, 1536, DIMC, 12);
        attn_kernel<<<rows1 / WINS, 256, 0, stream>>>(big, relb, r0, row0 / WINS);
    }

    // 4) x2b = bf16( x + roll(attn_out @ proj_w^T + proj_b, +SHIFT) )
    gemm_bt<1><<<(TOKENS / 128) * 4, 256, 0, stream>>>(
        r0, wb_proj, projb, x2b, nullptr, x, nullptr, DIMC, DIMC, 4);

    // 5) h2 = LN2(x2b) -> r0
    ln_kernel_bf<<<TOKENS / 4, 256, 0, stream>>>(x2b, n2w, n2b, r0);

    // 6+7) MLP chunked: g = gelu(h2 @ fc1^T); out = x2b + g @ fc2^T (fp32)
    const int rows2 = TOKENS / nc2;
    for (int c = 0; c < nc2; ++c) {
        const int row0 = c * rows2;
        gemm_bt<2><<<(rows2 / 128) * 16, 256, 0, stream>>>(
            r0 + (size_t)row0 * DIMC, wb_fc1, fc1b, big, nullptr, nullptr, nullptr, HIDDEN, DIMC, 16);
        gemm_bt<3><<<(rows2 / 128) * 4, 256, 0, stream>>>(
            big, wb_fc2, fc2b, nullptr, outp + (size_t)row0 * DIMC, nullptr,
            x2b + (size_t)row0 * DIMC, DIMC, HIDDEN, 4);
    }
}